// Round 2
// baseline (27567.523 us; speedup 1.0000x reference)
//
#include <hip/hip_runtime.h>
#include <stdint.h>

#define Bsz 128
#define Ssz 512
#define Vsz 600
#define Hsz 512
#define Tsz 121

// branch-free 6-op tanh: tanh(x) = 1 - 2/(1 + e^{2x}); exact at +/-inf, ~1e-6 abs err
__device__ __forceinline__ float fast_tanh(float x) {
  float e = __expf(x + x);
  return 1.0f - __fdividef(2.0f, 1.0f + e);
}

// ---------------- H_proj = batch_H @ W_i2h^T  [B*S, 600] x [512, 600]^T ----------------
__global__ __launch_bounds__(256) void k_hp(const float* __restrict__ bH,
                                            const float* __restrict__ Wi,
                                            float* __restrict__ Hp) {
  __shared__ float As[16][604];  // pad 604 to spread rg-group banks
  int m0 = blockIdx.x * 16;
  for (int idx = threadIdx.x; idx < 16 * 600; idx += 256) {
    int r = idx / 600, k = idx - r * 600;
    As[r][k] = bH[(size_t)(m0 + r) * 600 + k];
  }
  __syncthreads();
  int rg = threadIdx.x & 3, cg = threadIdx.x >> 2;
  int r0 = rg * 4;
  for (int pass = 0; pass < 2; ++pass) {
    int c0 = pass * 256 + cg * 4;
    float acc[4][4] = {};
    const float* w0p = Wi + (size_t)(c0 + 0) * 600;
    const float* w1p = Wi + (size_t)(c0 + 1) * 600;
    const float* w2p = Wi + (size_t)(c0 + 2) * 600;
    const float* w3p = Wi + (size_t)(c0 + 3) * 600;
    for (int k = 0; k < 600; k += 4) {
      float4 w0 = *(const float4*)(w0p + k);
      float4 w1 = *(const float4*)(w1p + k);
      float4 w2 = *(const float4*)(w2p + k);
      float4 w3 = *(const float4*)(w3p + k);
#pragma unroll
      for (int i = 0; i < 4; ++i) {
        float4 a = *(const float4*)&As[r0 + i][k];
        acc[i][0] += a.x * w0.x + a.y * w0.y + a.z * w0.z + a.w * w0.w;
        acc[i][1] += a.x * w1.x + a.y * w1.y + a.z * w1.z + a.w * w1.w;
        acc[i][2] += a.x * w2.x + a.y * w2.y + a.z * w2.z + a.w * w2.w;
        acc[i][3] += a.x * w3.x + a.y * w3.y + a.z * w3.z + a.w * w3.w;
      }
    }
#pragma unroll
    for (int i = 0; i < 4; ++i) {
      float4 o = make_float4(acc[i][0], acc[i][1], acc[i][2], acc[i][3]);
      *(float4*)&Hp[(size_t)(m0 + r0 + i) * Hsz + c0] = o;
    }
  }
}

// ---------------- pp = h_prev @ W_h2h^T + b_h2h ----------------
__global__ __launch_bounds__(512) void k_pp(const float* __restrict__ hprev,
                                            const float* __restrict__ W,
                                            const float* __restrict__ bias,
                                            float* __restrict__ pp) {
  __shared__ float hs[512];
  int b = blockIdx.x;
  hs[threadIdx.x] = hprev[b * Hsz + threadIdx.x];
  __syncthreads();
  int j = threadIdx.x;
  const float* wrow = W + (size_t)j * Hsz;
  float acc = bias[j];
#pragma unroll 4
  for (int k = 0; k < Hsz; k += 4) {
    float4 w = *(const float4*)(wrow + k);
    float4 h4 = *(const float4*)&hs[k];
    acc += w.x * h4.x + w.y * h4.y + w.z * h4.z + w.w * h4.w;
  }
  pp[b * Hsz + j] = acc;
}

// ---------------- e[b,s] = sum_h w[h]*tanh(Hp[b,s,h] + pp[b,h]) ----------------
// grid Bsz*4 blocks, 256 threads; 128 s per block, K split in 2 halves per thread
__global__ __launch_bounds__(256) void k_e(const float* __restrict__ Hp,
                                           const float* __restrict__ pp,
                                           const float* __restrict__ Wsc,
                                           float* __restrict__ ev) {
  __shared__ float pps[512];
  __shared__ float wss[512];
  __shared__ float part[128];
  int b = blockIdx.x >> 2, tile = blockIdx.x & 3;
  for (int i = threadIdx.x; i < 512; i += 256) {
    pps[i] = pp[b * Hsz + i];
    wss[i] = Wsc[i];
  }
  __syncthreads();
  int sl = threadIdx.x & 127, kh = threadIdx.x >> 7;
  int s = tile * 128 + sl;
  const float* hrow = Hp + ((size_t)b * Ssz + s) * Hsz + kh * 256;
  const float* pk = pps + kh * 256;
  const float* wk = wss + kh * 256;
  float acc = 0.f;
#pragma unroll 4
  for (int k = 0; k < 256; k += 4) {
    float4 h4 = *(const float4*)(hrow + k);
    float4 p4 = *(const float4*)(pk + k);
    float4 w4 = *(const float4*)(wk + k);
    acc += w4.x * fast_tanh(h4.x + p4.x);
    acc += w4.y * fast_tanh(h4.y + p4.y);
    acc += w4.z * fast_tanh(h4.z + p4.z);
    acc += w4.w * fast_tanh(h4.w + p4.w);
  }
  if (kh == 1) part[sl] = acc;
  __syncthreads();
  if (kh == 0) ev[b * Ssz + s] = acc + part[sl];
}

// ---------------- softmax(e) then context = alpha @ batch_H ----------------
// grid Bsz*3 blocks (v chunks of 200), 256 threads
__global__ __launch_bounds__(256) void k_ctx(const float* __restrict__ bH,
                                             const float* __restrict__ ev,
                                             float* __restrict__ ctx) {
  __shared__ float al[512];
  __shared__ float red[256];
  int b = blockIdx.x / 3, vc = blockIdx.x % 3;
  int tid = threadIdx.x;
  float e0 = ev[b * Ssz + tid], e1 = ev[b * Ssz + 256 + tid];
  // block max
  red[tid] = fmaxf(e0, e1);
  __syncthreads();
  for (int off = 128; off > 0; off >>= 1) {
    if (tid < off) red[tid] = fmaxf(red[tid], red[tid + off]);
    __syncthreads();
  }
  float m = red[0];
  __syncthreads();
  float x0 = __expf(e0 - m), x1 = __expf(e1 - m);
  red[tid] = x0 + x1;
  __syncthreads();
  for (int off = 128; off > 0; off >>= 1) {
    if (tid < off) red[tid] += red[tid + off];
    __syncthreads();
  }
  float inv = __fdividef(1.f, red[0]);
  __syncthreads();
  al[tid] = x0 * inv;
  al[tid + 256] = x1 * inv;
  __syncthreads();
  int v = vc * 200 + tid;
  if (tid < 200) {
    const float* bp = bH + (size_t)b * Ssz * Vsz + v;
    float acc = 0.f;
#pragma unroll 8
    for (int s = 0; s < Ssz; ++s) {
      acc += al[s] * bp[(size_t)s * Vsz];
    }
    ctx[b * Vsz + v] = acc;
  }
}

// ---------------- gates + LSTM pointwise ----------------
// grid dim3(16,16): (b-tiles of 8, h'-tiles of 32), 256 threads
__global__ __launch_bounds__(256) void k_gates(
    const float* __restrict__ ctx, const float* __restrict__ hprev,
    const float* __restrict__ Wih, const float* __restrict__ Whh,
    const float* __restrict__ bih, const float* __restrict__ bhh,
    const int* __restrict__ text, int t,
    const float* __restrict__ cin, float* __restrict__ cout,
    float* __restrict__ hout) {
  __shared__ float xs[8][1112];  // [ctx(600) | h(512)] per batch row
  int b0 = blockIdx.x * 8, j0 = blockIdx.y * 32;
  for (int idx = threadIdx.x; idx < 8 * 600; idx += 256) {
    int r = idx / 600, k = idx - r * 600;
    xs[r][k] = ctx[(b0 + r) * Vsz + k];
  }
  for (int idx = threadIdx.x; idx < 8 * 512; idx += 256) {
    int r = idx >> 9, k = idx & 511;
    xs[r][600 + k] = hprev[(b0 + r) * Hsz + k];
  }
  __syncthreads();
  int bi = threadIdx.x >> 5, jl = threadIdx.x & 31;
  int b = b0 + bi, j = j0 + jl;
  float acc[4];
#pragma unroll
  for (int g = 0; g < 4; ++g) acc[g] = bih[g * Hsz + j] + bhh[g * Hsz + j];
  const float* w0 = Wih + (size_t)(0 * Hsz + j) * 1200;
  const float* w1 = Wih + (size_t)(1 * Hsz + j) * 1200;
  const float* w2 = Wih + (size_t)(2 * Hsz + j) * 1200;
  const float* w3 = Wih + (size_t)(3 * Hsz + j) * 1200;
  const float* xr = xs[bi];
#pragma unroll 2
  for (int k = 0; k < 600; k += 4) {
    float4 x4 = *(const float4*)(xr + k);
    float4 a = *(const float4*)(w0 + k);
    acc[0] += x4.x * a.x + x4.y * a.y + x4.z * a.z + x4.w * a.w;
    float4 bq = *(const float4*)(w1 + k);
    acc[1] += x4.x * bq.x + x4.y * bq.y + x4.z * bq.z + x4.w * bq.w;
    float4 c4 = *(const float4*)(w2 + k);
    acc[2] += x4.x * c4.x + x4.y * c4.y + x4.z * c4.z + x4.w * c4.w;
    float4 d4 = *(const float4*)(w3 + k);
    acc[3] += x4.x * d4.x + x4.y * d4.y + x4.z * d4.z + x4.w * d4.w;
  }
  int tk = (t == 0) ? 0 : text[(size_t)b * Tsz + (t - 1)];
  acc[0] += w0[600 + tk];
  acc[1] += w1[600 + tk];
  acc[2] += w2[600 + tk];
  acc[3] += w3[600 + tk];
  const float* v0 = Whh + (size_t)(0 * Hsz + j) * Hsz;
  const float* v1 = Whh + (size_t)(1 * Hsz + j) * Hsz;
  const float* v2 = Whh + (size_t)(2 * Hsz + j) * Hsz;
  const float* v3 = Whh + (size_t)(3 * Hsz + j) * Hsz;
  const float* hr = xr + 600;
#pragma unroll 2
  for (int k = 0; k < 512; k += 4) {
    float4 x4 = *(const float4*)(hr + k);
    float4 a = *(const float4*)(v0 + k);
    acc[0] += x4.x * a.x + x4.y * a.y + x4.z * a.z + x4.w * a.w;
    float4 bq = *(const float4*)(v1 + k);
    acc[1] += x4.x * bq.x + x4.y * bq.y + x4.z * bq.z + x4.w * bq.w;
    float4 c4 = *(const float4*)(v2 + k);
    acc[2] += x4.x * c4.x + x4.y * c4.y + x4.z * c4.z + x4.w * c4.w;
    float4 d4 = *(const float4*)(v3 + k);
    acc[3] += x4.x * d4.x + x4.y * d4.y + x4.z * d4.z + x4.w * d4.w;
  }
  float ig = 1.f / (1.f + __expf(-acc[0]));
  float fg = 1.f / (1.f + __expf(-acc[1]));
  float gg = fast_tanh(acc[2]);
  float og = 1.f / (1.f + __expf(-acc[3]));
  float c = fg * cin[b * Hsz + j] + ig * gg;
  float hN = og * fast_tanh(c);
  cout[b * Hsz + j] = c;
  hout[b * Hsz + j] = hN;
}

// ---------------- probs = softmax(hid @ W_gen^T + b_gen) ----------------
// grid (B*T)/16 blocks, 256 threads; logits tile in registers then LDS softmax
__global__ __launch_bounds__(256) void k_gen(const float* __restrict__ hid,
                                             const float* __restrict__ Wg,
                                             const float* __restrict__ bg,
                                             float* __restrict__ out) {
  __shared__ float sm[16 * 600];  // union: hs[16][520] during GEMM, logits[16][600] after
  int m0 = blockIdx.x * 16;
  for (int idx = threadIdx.x; idx < 16 * 512; idx += 256) {
    int r = idx >> 9, k = idx & 511;
    int m = m0 + r;
    int bb = m / Tsz, tt = m - bb * Tsz;
    sm[r * 520 + k] = hid[((size_t)(tt + 1) * Bsz + bb) * Hsz + k];
  }
  __syncthreads();
  int rg = threadIdx.x & 3, cg = threadIdx.x >> 2;
  int r0 = rg * 4;
  bool has2 = (cg < 22);
  float acc[12][4] = {};
  for (int k = 0; k < 512; k += 4) {
    float4 a[4];
#pragma unroll
    for (int i = 0; i < 4; ++i) a[i] = *(const float4*)&sm[(r0 + i) * 520 + k];
#pragma unroll
    for (int p = 0; p < 3; ++p) {
      if (p == 2 && !has2) continue;
#pragma unroll
      for (int i = 0; i < 4; ++i) {
        int c = p * 256 + cg * 4 + i;
        float4 w = *(const float4*)&Wg[(size_t)c * Hsz + k];
        int ci = p * 4 + i;
#pragma unroll
        for (int r = 0; r < 4; ++r)
          acc[ci][r] += a[r].x * w.x + a[r].y * w.y + a[r].z * w.z + a[r].w * w.w;
      }
    }
  }
  __syncthreads();
#pragma unroll
  for (int p = 0; p < 3; ++p) {
    if (p == 2 && !has2) continue;
#pragma unroll
    for (int i = 0; i < 4; ++i) {
      int c = p * 256 + cg * 4 + i;
      float bgc = bg[c];
#pragma unroll
      for (int r = 0; r < 4; ++r) sm[(r0 + r) * 600 + c] = acc[p * 4 + i][r] + bgc;
    }
  }
  __syncthreads();
  int wv = threadIdx.x >> 6, ln = threadIdx.x & 63;
  for (int r = wv; r < 16; r += 4) {
    float* row = sm + r * 600;
    float mx = -1e30f;
    for (int c = ln; c < 600; c += 64) mx = fmaxf(mx, row[c]);
#pragma unroll
    for (int off = 32; off > 0; off >>= 1) mx = fmaxf(mx, __shfl_xor(mx, off));
    float ssum = 0.f;
    for (int c = ln; c < 600; c += 64) {
      float ex = __expf(row[c] - mx);
      row[c] = ex;
      ssum += ex;
    }
#pragma unroll
    for (int off = 32; off > 0; off >>= 1) ssum += __shfl_xor(ssum, off);
    float inv = __fdividef(1.f, ssum);
    float* op = out + (size_t)(m0 + r) * 600;
    for (int c = ln; c < 600; c += 64) op[c] = row[c] * inv;
  }
}

extern "C" void kernel_launch(void* const* d_in, const int* in_sizes, int n_in,
                              void* d_out, int out_size, void* d_ws, size_t ws_size,
                              hipStream_t stream) {
  const float* bH = (const float*)d_in[0];
  const int* text = (const int*)d_in[1];  // harness converts int64 -> int32
  const float* Wi2h = (const float*)d_in[2];
  const float* Wh2h = (const float*)d_in[3];
  const float* bh2h = (const float*)d_in[4];
  const float* Wsc = (const float*)d_in[5];
  const float* Wih = (const float*)d_in[6];
  const float* Whh = (const float*)d_in[7];
  const float* bih = (const float*)d_in[8];
  const float* bhh = (const float*)d_in[9];
  const float* Wg = (const float*)d_in[10];
  const float* bg = (const float*)d_in[11];
  float* out = (float*)d_out;

  float* ws = (float*)d_ws;
  size_t off = 0;
  float* Hp = ws + off;  off += (size_t)Bsz * Ssz * Hsz;        // 134 MB
  float* hid = ws + off; off += (size_t)(Tsz + 1) * Bsz * Hsz;  // 32 MB
  float* cb = ws + off;  off += (size_t)2 * Bsz * Hsz;
  float* pp = ws + off;  off += (size_t)Bsz * Hsz;
  float* ev = ws + off;  off += (size_t)Bsz * Ssz;
  float* ctx = ws + off; off += (size_t)Bsz * Vsz;

  hipMemsetAsync(hid, 0, (size_t)Bsz * Hsz * sizeof(float), stream);  // h0 = 0
  hipMemsetAsync(cb, 0, (size_t)Bsz * Hsz * sizeof(float), stream);   // c0 = 0

  k_hp<<<(Bsz * Ssz) / 16, 256, 0, stream>>>(bH, Wi2h, Hp);

  for (int t = 0; t < Tsz; ++t) {
    const float* hprev = hid + (size_t)t * Bsz * Hsz;
    float* hnext = hid + (size_t)(t + 1) * Bsz * Hsz;
    const float* cin = cb + (size_t)(t & 1) * Bsz * Hsz;
    float* cout = cb + (size_t)((t + 1) & 1) * Bsz * Hsz;
    k_pp<<<Bsz, 512, 0, stream>>>(hprev, Wh2h, bh2h, pp);
    k_e<<<Bsz * 4, 256, 0, stream>>>(Hp, pp, Wsc, ev);
    k_ctx<<<Bsz * 3, 256, 0, stream>>>(bH, ev, ctx);
    k_gates<<<dim3(16, 16), 256, 0, stream>>>(ctx, hprev, Wih, Whh, bih, bhh,
                                              text, t, cin, cout, hnext);
  }

  k_gen<<<(Bsz * Tsz) / 16, 256, 0, stream>>>(hid, Wg, bg, out);
}

// Round 3
// 23741.766 us; speedup vs baseline: 1.1611x; 1.1611x over previous
//
#include <hip/hip_runtime.h>
#include <stdint.h>

#define Bsz 128
#define Ssz 512
#define Vsz 600
#define Hsz 512
#define Tsz 121

// branch-free 6-op tanh: tanh(x) = 1 - 2/(1 + e^{2x}); exact at +/-inf, ~1e-6 abs err
__device__ __forceinline__ float fast_tanh(float x) {
  float e = __expf(x + x);
  return 1.0f - __fdividef(2.0f, 1.0f + e);
}

// ---------------- H_proj = batch_H @ W_i2h^T  [B*S, 600] x [512, 600]^T ----------------
__global__ __launch_bounds__(256) void k_hp(const float* __restrict__ bH,
                                            const float* __restrict__ Wi,
                                            float* __restrict__ Hp) {
  __shared__ float As[16][604];  // pad 604 to spread rg-group banks
  int m0 = blockIdx.x * 16;
  for (int idx = threadIdx.x; idx < 16 * 600; idx += 256) {
    int r = idx / 600, k = idx - r * 600;
    As[r][k] = bH[(size_t)(m0 + r) * 600 + k];
  }
  __syncthreads();
  int rg = threadIdx.x & 3, cg = threadIdx.x >> 2;
  int r0 = rg * 4;
  for (int pass = 0; pass < 2; ++pass) {
    int c0 = pass * 256 + cg * 4;
    float acc[4][4] = {};
    const float* w0p = Wi + (size_t)(c0 + 0) * 600;
    const float* w1p = Wi + (size_t)(c0 + 1) * 600;
    const float* w2p = Wi + (size_t)(c0 + 2) * 600;
    const float* w3p = Wi + (size_t)(c0 + 3) * 600;
    for (int k = 0; k < 600; k += 4) {
      float4 w0 = *(const float4*)(w0p + k);
      float4 w1 = *(const float4*)(w1p + k);
      float4 w2 = *(const float4*)(w2p + k);
      float4 w3 = *(const float4*)(w3p + k);
#pragma unroll
      for (int i = 0; i < 4; ++i) {
        float4 a = *(const float4*)&As[r0 + i][k];
        acc[i][0] += a.x * w0.x + a.y * w0.y + a.z * w0.z + a.w * w0.w;
        acc[i][1] += a.x * w1.x + a.y * w1.y + a.z * w1.z + a.w * w1.w;
        acc[i][2] += a.x * w2.x + a.y * w2.y + a.z * w2.z + a.w * w2.w;
        acc[i][3] += a.x * w3.x + a.y * w3.y + a.z * w3.z + a.w * w3.w;
      }
    }
#pragma unroll
    for (int i = 0; i < 4; ++i) {
      float4 o = make_float4(acc[i][0], acc[i][1], acc[i][2], acc[i][3]);
      *(float4*)&Hp[(size_t)(m0 + r0 + i) * Hsz + c0] = o;
    }
  }
}

// ---------------- pp = h_prev @ W_h2h^T + b_h2h ----------------
// grid dim3(Bsz, 4): (batch, j-quad of 128); 256 thr = 128 j-lanes x 2 k-halves
__global__ __launch_bounds__(256) void k_pp(const float* __restrict__ hprev,
                                            const float* __restrict__ W,
                                            const float* __restrict__ bias,
                                            float* __restrict__ pp) {
  __shared__ float hs[512];
  __shared__ float part[128];
  int b = blockIdx.x, jq = blockIdx.y;
  int tid = threadIdx.x;
  hs[tid] = hprev[b * Hsz + tid];
  hs[tid + 256] = hprev[b * Hsz + 256 + tid];
  __syncthreads();
  int jl = tid & 127, kh = tid >> 7;
  int j = jq * 128 + jl;
  const float* wrow = W + (size_t)j * Hsz + kh * 256;
  const float* hp = hs + kh * 256;
  float acc = 0.f;
#pragma unroll 4
  for (int k = 0; k < 256; k += 4) {
    float4 w = *(const float4*)(wrow + k);
    float4 h4 = *(const float4*)(hp + k);
    acc += w.x * h4.x + w.y * h4.y + w.z * h4.z + w.w * h4.w;
  }
  if (kh == 1) part[jl] = acc;
  __syncthreads();
  if (kh == 0) pp[b * Hsz + j] = acc + part[jl] + bias[j];
}

// ---------------- e[b,s] = sum_h w[h]*tanh(Hp[b,s,h] + pp[b,h]) ----------------
// grid Bsz*4 blocks, 256 threads; 128 s per block, K split in 2 halves per thread
__global__ __launch_bounds__(256) void k_e(const float* __restrict__ Hp,
                                           const float* __restrict__ pp,
                                           const float* __restrict__ Wsc,
                                           float* __restrict__ ev) {
  __shared__ float pps[512];
  __shared__ float wss[512];
  __shared__ float part[128];
  int b = blockIdx.x >> 2, tile = blockIdx.x & 3;
  for (int i = threadIdx.x; i < 512; i += 256) {
    pps[i] = pp[b * Hsz + i];
    wss[i] = Wsc[i];
  }
  __syncthreads();
  int sl = threadIdx.x & 127, kh = threadIdx.x >> 7;
  int s = tile * 128 + sl;
  const float* hrow = Hp + ((size_t)b * Ssz + s) * Hsz + kh * 256;
  const float* pk = pps + kh * 256;
  const float* wk = wss + kh * 256;
  float acc = 0.f;
#pragma unroll 4
  for (int k = 0; k < 256; k += 4) {
    float4 h4 = *(const float4*)(hrow + k);
    float4 p4 = *(const float4*)(pk + k);
    float4 w4 = *(const float4*)(wk + k);
    acc += w4.x * fast_tanh(h4.x + p4.x);
    acc += w4.y * fast_tanh(h4.y + p4.y);
    acc += w4.z * fast_tanh(h4.z + p4.z);
    acc += w4.w * fast_tanh(h4.w + p4.w);
  }
  if (kh == 1) part[sl] = acc;
  __syncthreads();
  if (kh == 0) ev[b * Ssz + s] = acc + part[sl];
}

// ---------------- softmax(e) then context = alpha @ batch_H ----------------
// grid dim3(Bsz, 10): (batch, v-chunk of 64); 256 thr = 64 v-lanes x 4 s-groups
__global__ __launch_bounds__(256) void k_ctx(const float* __restrict__ bH,
                                             const float* __restrict__ ev,
                                             float* __restrict__ ctx) {
  __shared__ float al[512];
  __shared__ float wred[8];
  __shared__ float part[4][64];
  int b = blockIdx.x, vc = blockIdx.y;
  int tid = threadIdx.x;
  int wv = tid >> 6, ln = tid & 63;
  float e0 = ev[b * Ssz + tid], e1 = ev[b * Ssz + 256 + tid];
  float m = fmaxf(e0, e1);
#pragma unroll
  for (int off = 32; off > 0; off >>= 1) m = fmaxf(m, __shfl_xor(m, off));
  if (ln == 0) wred[wv] = m;
  __syncthreads();
  m = fmaxf(fmaxf(wred[0], wred[1]), fmaxf(wred[2], wred[3]));
  float x0 = __expf(e0 - m), x1 = __expf(e1 - m);
  float sum = x0 + x1;
#pragma unroll
  for (int off = 32; off > 0; off >>= 1) sum += __shfl_xor(sum, off);
  if (ln == 0) wred[4 + wv] = sum;
  __syncthreads();
  sum = wred[4] + wred[5] + wred[6] + wred[7];
  float inv = __fdividef(1.f, sum);
  al[tid] = x0 * inv;
  al[tid + 256] = x1 * inv;
  __syncthreads();
  int vl = ln, sg = wv;  // 64 v-lanes, 4 s-groups of 128
  int v = vc * 64 + vl;
  float acc = 0.f;
  if (v < Vsz) {
    const float* bp = bH + (size_t)b * Ssz * Vsz + (size_t)sg * 128 * Vsz + v;
    const float* ap = al + sg * 128;
#pragma unroll 8
    for (int s2 = 0; s2 < 128; ++s2) acc += ap[s2] * bp[(size_t)s2 * Vsz];
  }
  part[sg][vl] = acc;
  __syncthreads();
  if (sg == 0 && v < Vsz)
    ctx[b * Vsz + v] = part[0][vl] + part[1][vl] + part[2][vl] + part[3][vl];
}

// ---------------- gates + LSTM pointwise ----------------
// grid dim3(16,16): (b-tiles of 8, h'-tiles of 32), 256 threads
__global__ __launch_bounds__(256) void k_gates(
    const float* __restrict__ ctx, const float* __restrict__ hprev,
    const float* __restrict__ Wih, const float* __restrict__ Whh,
    const float* __restrict__ bih, const float* __restrict__ bhh,
    const int* __restrict__ text, int t,
    const float* __restrict__ cin, float* __restrict__ cout,
    float* __restrict__ hout) {
  __shared__ float xs[8][1112];  // [ctx(600) | h(512)] per batch row
  int b0 = blockIdx.x * 8, j0 = blockIdx.y * 32;
  for (int idx = threadIdx.x; idx < 8 * 600; idx += 256) {
    int r = idx / 600, k = idx - r * 600;
    xs[r][k] = ctx[(b0 + r) * Vsz + k];
  }
  for (int idx = threadIdx.x; idx < 8 * 512; idx += 256) {
    int r = idx >> 9, k = idx & 511;
    xs[r][600 + k] = hprev[(b0 + r) * Hsz + k];
  }
  __syncthreads();
  int bi = threadIdx.x >> 5, jl = threadIdx.x & 31;
  int b = b0 + bi, j = j0 + jl;
  float acc[4];
#pragma unroll
  for (int g = 0; g < 4; ++g) acc[g] = bih[g * Hsz + j] + bhh[g * Hsz + j];
  const float* w0 = Wih + (size_t)(0 * Hsz + j) * 1200;
  const float* w1 = Wih + (size_t)(1 * Hsz + j) * 1200;
  const float* w2 = Wih + (size_t)(2 * Hsz + j) * 1200;
  const float* w3 = Wih + (size_t)(3 * Hsz + j) * 1200;
  const float* xr = xs[bi];
#pragma unroll 2
  for (int k = 0; k < 600; k += 4) {
    float4 x4 = *(const float4*)(xr + k);
    float4 a = *(const float4*)(w0 + k);
    acc[0] += x4.x * a.x + x4.y * a.y + x4.z * a.z + x4.w * a.w;
    float4 bq = *(const float4*)(w1 + k);
    acc[1] += x4.x * bq.x + x4.y * bq.y + x4.z * bq.z + x4.w * bq.w;
    float4 c4 = *(const float4*)(w2 + k);
    acc[2] += x4.x * c4.x + x4.y * c4.y + x4.z * c4.z + x4.w * c4.w;
    float4 d4 = *(const float4*)(w3 + k);
    acc[3] += x4.x * d4.x + x4.y * d4.y + x4.z * d4.z + x4.w * d4.w;
  }
  int tk = (t == 0) ? 0 : text[(size_t)b * Tsz + (t - 1)];
  acc[0] += w0[600 + tk];
  acc[1] += w1[600 + tk];
  acc[2] += w2[600 + tk];
  acc[3] += w3[600 + tk];
  const float* v0 = Whh + (size_t)(0 * Hsz + j) * Hsz;
  const float* v1 = Whh + (size_t)(1 * Hsz + j) * Hsz;
  const float* v2 = Whh + (size_t)(2 * Hsz + j) * Hsz;
  const float* v3 = Whh + (size_t)(3 * Hsz + j) * Hsz;
  const float* hr = xr + 600;
#pragma unroll 2
  for (int k = 0; k < 512; k += 4) {
    float4 x4 = *(const float4*)(hr + k);
    float4 a = *(const float4*)(v0 + k);
    acc[0] += x4.x * a.x + x4.y * a.y + x4.z * a.z + x4.w * a.w;
    float4 bq = *(const float4*)(v1 + k);
    acc[1] += x4.x * bq.x + x4.y * bq.y + x4.z * bq.z + x4.w * bq.w;
    float4 c4 = *(const float4*)(v2 + k);
    acc[2] += x4.x * c4.x + x4.y * c4.y + x4.z * c4.z + x4.w * c4.w;
    float4 d4 = *(const float4*)(v3 + k);
    acc[3] += x4.x * d4.x + x4.y * d4.y + x4.z * d4.z + x4.w * d4.w;
  }
  float ig = 1.f / (1.f + __expf(-acc[0]));
  float fg = 1.f / (1.f + __expf(-acc[1]));
  float gg = fast_tanh(acc[2]);
  float og = 1.f / (1.f + __expf(-acc[3]));
  float c = fg * cin[b * Hsz + j] + ig * gg;
  float hN = og * fast_tanh(c);
  cout[b * Hsz + j] = c;
  hout[b * Hsz + j] = hN;
}

// ---------------- probs = softmax(hid @ W_gen^T + b_gen) ----------------
// grid (B*T)/16 blocks, 256 threads; logits tile in registers then LDS softmax
__global__ __launch_bounds__(256) void k_gen(const float* __restrict__ hid,
                                             const float* __restrict__ Wg,
                                             const float* __restrict__ bg,
                                             float* __restrict__ out) {
  __shared__ float sm[16 * 600];  // union: hs[16][520] during GEMM, logits[16][600] after
  int m0 = blockIdx.x * 16;
  for (int idx = threadIdx.x; idx < 16 * 512; idx += 256) {
    int r = idx >> 9, k = idx & 511;
    int m = m0 + r;
    int bb = m / Tsz, tt = m - bb * Tsz;
    sm[r * 520 + k] = hid[((size_t)(tt + 1) * Bsz + bb) * Hsz + k];
  }
  __syncthreads();
  int rg = threadIdx.x & 3, cg = threadIdx.x >> 2;
  int r0 = rg * 4;
  bool has2 = (cg < 22);
  float acc[12][4] = {};
  for (int k = 0; k < 512; k += 4) {
    float4 a[4];
#pragma unroll
    for (int i = 0; i < 4; ++i) a[i] = *(const float4*)&sm[(r0 + i) * 520 + k];
#pragma unroll
    for (int p = 0; p < 3; ++p) {
      if (p == 2 && !has2) continue;
#pragma unroll
      for (int i = 0; i < 4; ++i) {
        int c = p * 256 + cg * 4 + i;
        float4 w = *(const float4*)&Wg[(size_t)c * Hsz + k];
        int ci = p * 4 + i;
#pragma unroll
        for (int r = 0; r < 4; ++r)
          acc[ci][r] += a[r].x * w.x + a[r].y * w.y + a[r].z * w.z + a[r].w * w.w;
      }
    }
  }
  __syncthreads();
#pragma unroll
  for (int p = 0; p < 3; ++p) {
    if (p == 2 && !has2) continue;
#pragma unroll
    for (int i = 0; i < 4; ++i) {
      int c = p * 256 + cg * 4 + i;
      float bgc = bg[c];
#pragma unroll
      for (int r = 0; r < 4; ++r) sm[(r0 + r) * 600 + c] = acc[p * 4 + i][r] + bgc;
    }
  }
  __syncthreads();
  int wv = threadIdx.x >> 6, ln = threadIdx.x & 63;
  for (int r = wv; r < 16; r += 4) {
    float* row = sm + r * 600;
    float mx = -1e30f;
    for (int c = ln; c < 600; c += 64) mx = fmaxf(mx, row[c]);
#pragma unroll
    for (int off = 32; off > 0; off >>= 1) mx = fmaxf(mx, __shfl_xor(mx, off));
    float ssum = 0.f;
    for (int c = ln; c < 600; c += 64) {
      float ex = __expf(row[c] - mx);
      row[c] = ex;
      ssum += ex;
    }
#pragma unroll
    for (int off = 32; off > 0; off >>= 1) ssum += __shfl_xor(ssum, off);
    float inv = __fdividef(1.f, ssum);
    float* op = out + (size_t)(m0 + r) * 600;
    for (int c = ln; c < 600; c += 64) op[c] = row[c] * inv;
  }
}

extern "C" void kernel_launch(void* const* d_in, const int* in_sizes, int n_in,
                              void* d_out, int out_size, void* d_ws, size_t ws_size,
                              hipStream_t stream) {
  const float* bH = (const float*)d_in[0];
  const int* text = (const int*)d_in[1];  // harness converts int64 -> int32
  const float* Wi2h = (const float*)d_in[2];
  const float* Wh2h = (const float*)d_in[3];
  const float* bh2h = (const float*)d_in[4];
  const float* Wsc = (const float*)d_in[5];
  const float* Wih = (const float*)d_in[6];
  const float* Whh = (const float*)d_in[7];
  const float* bih = (const float*)d_in[8];
  const float* bhh = (const float*)d_in[9];
  const float* Wg = (const float*)d_in[10];
  const float* bg = (const float*)d_in[11];
  float* out = (float*)d_out;

  float* ws = (float*)d_ws;
  size_t off = 0;
  float* Hp = ws + off;  off += (size_t)Bsz * Ssz * Hsz;        // 134 MB
  float* hid = ws + off; off += (size_t)(Tsz + 1) * Bsz * Hsz;  // 32 MB
  float* cb = ws + off;  off += (size_t)2 * Bsz * Hsz;
  float* pp = ws + off;  off += (size_t)Bsz * Hsz;
  float* ev = ws + off;  off += (size_t)Bsz * Ssz;
  float* ctx = ws + off; off += (size_t)Bsz * Vsz;

  hipMemsetAsync(hid, 0, (size_t)Bsz * Hsz * sizeof(float), stream);  // h0 = 0
  hipMemsetAsync(cb, 0, (size_t)Bsz * Hsz * sizeof(float), stream);   // c0 = 0

  k_hp<<<(Bsz * Ssz) / 16, 256, 0, stream>>>(bH, Wi2h, Hp);

  for (int t = 0; t < Tsz; ++t) {
    const float* hprev = hid + (size_t)t * Bsz * Hsz;
    float* hnext = hid + (size_t)(t + 1) * Bsz * Hsz;
    const float* cin = cb + (size_t)(t & 1) * Bsz * Hsz;
    float* cout = cb + (size_t)((t + 1) & 1) * Bsz * Hsz;
    k_pp<<<dim3(Bsz, 4), 256, 0, stream>>>(hprev, Wh2h, bh2h, pp);
    k_e<<<Bsz * 4, 256, 0, stream>>>(Hp, pp, Wsc, ev);
    k_ctx<<<dim3(Bsz, 10), 256, 0, stream>>>(bH, ev, ctx);
    k_gates<<<dim3(16, 16), 256, 0, stream>>>(ctx, hprev, Wih, Whh, bih, bhh,
                                              text, t, cin, cout, hnext);
  }

  k_gen<<<(Bsz * Tsz) / 16, 256, 0, stream>>>(hid, Wg, bg, out);
}